// Round 14
// baseline (26.827 us; speedup 1.0000x reference)
//
#include <hip/hip_runtime.h>
#include <hip/hip_bf16.h>
#include <math.h>

// Problem: B=8, M=N=4096, C=3, f32. Avg-Hausdorff (Chamfer), out (8,).
// d2(a,b) = sa + (sb - 2 a.b); paren term = rank-16 bf16 MFMA with fp32
// hi/lo splitting (validated R9-R13: absmax 0.0). Swapped operands
// (D = Target x Query) keep the target-min lane-local (R12 fix).
//
// R13: NSEG=1 -> per-query min completes inside one block (all 4096 targets
// staged in 128 KB LDS); sqrt+sum fused into k1 tail; k2 = 1 tiny block.
// Grid 256 = 1 block/CU; removes the 1 MB pmin round-trip + big k2 dispatch.
constexpr int NB   = 8;
constexpr int NPTS = 4096;
constexpr int TPB  = 256;

typedef __attribute__((ext_vector_type(8)))  short  short8;
typedef __attribute__((ext_vector_type(16))) float  f32x16;

__device__ inline unsigned short f2bf(float v) {
    __hip_bfloat16 t = __float2bfloat16(v);
    return *reinterpret_cast<unsigned short*>(&t);
}
__device__ inline float bf2f(unsigned short u) {
    __hip_bfloat16 t = *reinterpret_cast<__hip_bfloat16*>(&u);
    return __bfloat162float(t);
}

// k1: grid = 16 g x 16 qb = 256 blocks (1/CU), 256 thr (4 waves).
// Block: 256 queries x ALL 4096 targets. Wave: 2 query fragments.
// 64 pair-iters x {2 lane-contiguous ds_read_b128 + 4 MFMA(T,Q) + 32 min3}.
// Tail: lane-local fold + 1 shfl_xor(32) -> per-query min; + sa (f32, from
// registers), clamp, sqrt; wave+block sum -> partial[g*16+qb].
__global__ __launch_bounds__(TPB) void hausdorff_mfma_kernel(
    const float* __restrict__ s1, const float* __restrict__ s2,
    float* __restrict__ partial)
{
    __shared__ short8 blds[2 * NPTS];   // 128 KB, slot-ordered target frags

    int bid = blockIdx.x;
    int qb  = bid & 15;
    int g   = bid >> 4;                // dir*8 + batch
    int b   = g & 7, dir = g >> 3;

    const float* Q = dir ? s2 : s1;    // query set
    const float* T = dir ? s1 : s2;    // target set

    int tid = threadIdx.x;
    int wid = tid >> 6, l = tid & 63;
    int c = l & 31, h = l >> 5;

    // ---- Encode ALL 4096 targets into LDS (16 points/thread) ----
    const float* tsrc = T + (size_t)b * NPTS * 3;
    #pragma unroll 4
    for (int k = 0; k < 16; ++k) {
        int p = k * TPB + tid;           // 0..4095
        float x = tsrc[p*3+0], y = tsrc[p*3+1], z = tsrc[p*3+2];
        float sq = fmaf(z, z, fmaf(y, y, x * x));
        float tx = -2.0f*x, ty = -2.0f*y, tz = -2.0f*z;
        unsigned short thx = f2bf(tx), thy = f2bf(ty), thz = f2bf(tz);
        unsigned short tlx = f2bf(tx - bf2f(thx));
        unsigned short tly = f2bf(ty - bf2f(thy));
        unsigned short tlz = f2bf(tz - bf2f(thz));
        unsigned short sqh = f2bf(sq);
        unsigned short sql = f2bf(sq - bf2f(sqh));
        short8 tLo = {(short)thx,(short)thy,(short)thz,(short)thx,(short)thy,(short)thz,(short)sqh,(short)sql};
        short8 tHi = {(short)tlx,(short)tly,(short)tlz,0,0,0,0,0};
        int slot = (p >> 5) * 64 + (p & 31);
        blds[slot]      = tLo;
        blds[slot + 32] = tHi;
    }

    // ---- Encode this wave's 2 query fragments; keep raw coords for sa ----
    short8 qfr[2]; float qx[2], qy[2], qz[2];
    #pragma unroll
    for (int f = 0; f < 2; ++f) {
        int qidx = qb * 256 + wid * 64 + f * 32 + c;
        const float* qp = Q + ((size_t)b * NPTS + qidx) * 3;
        float x = qp[0], y = qp[1], z = qp[2];
        qx[f] = x; qy[f] = y; qz[f] = z;
        unsigned short ahx = f2bf(x), ahy = f2bf(y), ahz = f2bf(z);
        if (h == 0) {
            unsigned short alx = f2bf(x - bf2f(ahx));
            unsigned short aly = f2bf(y - bf2f(ahy));
            unsigned short alz = f2bf(z - bf2f(ahz));
            unsigned short one = 0x3F80;
            qfr[f] = short8{(short)ahx,(short)ahy,(short)ahz,
                            (short)alx,(short)aly,(short)alz,(short)one,(short)one};
        } else {
            qfr[f] = short8{(short)ahx,(short)ahy,(short)ahz,0,0,0,0,0};
        }
    }
    __syncthreads();

    f32x16 zero, acc0, acc1;
    #pragma unroll
    for (int r = 0; r < 16; ++r) { zero[r] = 0.0f; acc0[r] = 3.4e38f; acc1[r] = 3.4e38f; }

    #pragma unroll 2
    for (int i = 0; i < 64; ++i) {            // 128 target tiles, in pairs
        short8 t0 = blds[(2*i  ) * 64 + l];    // lane-contiguous b128
        short8 t1 = blds[(2*i+1) * 64 + l];
        f32x16 d0 = __builtin_amdgcn_mfma_f32_32x32x16_bf16(t0, qfr[0], zero, 0, 0, 0);
        f32x16 d1 = __builtin_amdgcn_mfma_f32_32x32x16_bf16(t1, qfr[0], zero, 0, 0, 0);
        #pragma unroll
        for (int r = 0; r < 16; ++r)
            acc0[r] = fminf(fminf(acc0[r], d0[r]), d1[r]);   // v_min3
        f32x16 e0 = __builtin_amdgcn_mfma_f32_32x32x16_bf16(t0, qfr[1], zero, 0, 0, 0);
        f32x16 e1 = __builtin_amdgcn_mfma_f32_32x32x16_bf16(t1, qfr[1], zero, 0, 0, 0);
        #pragma unroll
        for (int r = 0; r < 16; ++r)
            acc1[r] = fminf(fminf(acc1[r], e0[r]), e1[r]);
    }

    // ---- Tail: per-query min -> + sa -> sqrt -> wave & block sum ----
    float s = 0.0f;
    #pragma unroll
    for (int f = 0; f < 2; ++f) {
        f32x16& a = f ? acc1 : acc0;
        float v = a[0];
        #pragma unroll
        for (int r = 1; r < 16; ++r) v = fminf(v, a[r]);
        v = fminf(v, __shfl_xor(v, 32, 64));   // combine h halves
        float sa = fmaf(qz[f], qz[f], fmaf(qy[f], qy[f], qx[f] * qx[f]));
        s += sqrtf(fmaxf(sa + v, 0.0f));
    }
    if (h) s = 0.0f;                           // h halves are duplicates
    for (int off = 32; off > 0; off >>= 1)
        s += __shfl_down(s, off, 64);

    __syncthreads();                           // blds reuse guard
    float* red = reinterpret_cast<float*>(blds);
    if (l == 0) red[wid] = s;
    __syncthreads();
    if (tid == 0)
        partial[bid] = red[0] + red[1] + red[2] + red[3];
}

// k2: 1 block, 64 threads: sum 16 qb-partials per g, combine dirs, /M.
__global__ __launch_bounds__(64) void final_kernel(
    const float* __restrict__ partial, float* __restrict__ out)
{
    int l = threadIdx.x;
    float s = 0.0f;
    if (l < 16) {
        #pragma unroll
        for (int j = 0; j < 16; ++j)
            s += partial[l * 16 + j];
    }
    float other = __shfl(s, l + 8, 64);        // lane b<8 gets g=8+b sum
    if (l < NB)
        out[l] = (s + other) * (1.0f / (float)NPTS);
}

extern "C" void kernel_launch(void* const* d_in, const int* in_sizes, int n_in,
                              void* d_out, int out_size, void* d_ws, size_t ws_size,
                              hipStream_t stream) {
    const float* set1 = (const float*)d_in[0];
    const float* set2 = (const float*)d_in[1];
    float* out     = (float*)d_out;
    float* partial = (float*)d_ws;   // 256 floats

    hausdorff_mfma_kernel<<<256, TPB, 0, stream>>>(set1, set2, partial);
    final_kernel<<<1, 64, 0, stream>>>(partial, out);
}

// Round 15
// 18.227 us; speedup vs baseline: 1.4718x; 1.4718x over previous
//
#include <hip/hip_runtime.h>
#include <hip/hip_bf16.h>
#include <math.h>

// Problem: B=8, M=N=4096, C=3, f32. Avg-Hausdorff (Chamfer), out (8,).
// d2(a,b) = sa + (sb - 2 a.b); paren term = rank-16 bf16 MFMA with fp32
// hi/lo splitting (validated R9-R13: absmax 0.0). Swapped operands
// (D = Target x Query) keep the target-min lane-local (R12 fix).
//
// R14 = R12 with the k1 inner loop DE-PRESSURED: sequential MFMA pairs
// reusing d0/d1 (32 transient VGPRs, was 128 with unroll-2 x 4 results),
// so the (256,4) launch bound (128 VGPR cap) holds without scratch spill.
constexpr int NB   = 8;
constexpr int NPTS = 4096;
constexpr int NSEG = 4;            // n segments per (dir,batch)
constexpr int NN   = NPTS / NSEG;  // 1024 target points per block

typedef __attribute__((ext_vector_type(8)))  short  short8;
typedef __attribute__((ext_vector_type(16))) float  f32x16;

__device__ inline unsigned short f2bf(float v) {
    __hip_bfloat16 t = __float2bfloat16(v);
    return *reinterpret_cast<unsigned short*>(&t);
}
__device__ inline float bf2f(unsigned short u) {
    __hip_bfloat16 t = *reinterpret_cast<__hip_bfloat16*>(&u);
    return __bfloat162float(t);
}

// k1: grid = 16 g x 16 qblk x 4 nseg = 1024 blocks (4/CU, 4 waves/SIMD).
// Block: 256 query rows x 1024 target points. Wave: 2 query fragments.
// Per iter: 2 lane-contiguous ds_read_b128 + 4 MFMA(T,Q) + 32 min3,
// sequenced to keep <=2 f32x16 transients live.
__global__ __launch_bounds__(256, 4) void mfma_min_kernel(
    const float* __restrict__ s1, const float* __restrict__ s2,
    float* __restrict__ pmin)
{
    __shared__ short8 blds[2048];   // 32 KB, slot-ordered target fragments

    int bid  = blockIdx.x;
    int nseg = bid & 3;
    int qb   = (bid >> 2) & 15;
    int g    = bid >> 6;               // dir*8 + batch
    int b    = g & 7, dir = g >> 3;

    const float* Q    = dir ? s2 : s1;   // query set
    const float* Tset = dir ? s1 : s2;   // target set

    int tid = threadIdx.x;
    int wid = tid >> 6, l = tid & 63;
    int c = l & 31, h = l >> 5;

    // ---- Encode target segment into LDS (each thread: 4 points) ----
    const float* tsrc = Tset + ((size_t)b * NPTS + (size_t)nseg * NN) * 3;
    #pragma unroll
    for (int k = 0; k < 4; ++k) {
        int p = k * 256 + tid;           // 0..1023
        float x = tsrc[p*3+0], y = tsrc[p*3+1], z = tsrc[p*3+2];
        float sq = fmaf(z, z, fmaf(y, y, x * x));
        float tx = -2.0f*x, ty = -2.0f*y, tz = -2.0f*z;
        unsigned short thx = f2bf(tx), thy = f2bf(ty), thz = f2bf(tz);
        unsigned short tlx = f2bf(tx - bf2f(thx));
        unsigned short tly = f2bf(ty - bf2f(thy));
        unsigned short tlz = f2bf(tz - bf2f(thz));
        unsigned short sqh = f2bf(sq);
        unsigned short sql = f2bf(sq - bf2f(sqh));
        short8 tLo = {(short)thx,(short)thy,(short)thz,(short)thx,(short)thy,(short)thz,(short)sqh,(short)sql};
        short8 tHi = {(short)tlx,(short)tly,(short)tlz,0,0,0,0,0};
        int slot = (p >> 5) * 64 + (p & 31);
        blds[slot]      = tLo;
        blds[slot + 32] = tHi;
    }

    // ---- Encode this wave's 2 query fragments (64 queries) ----
    short8 qfr[2];
    #pragma unroll
    for (int f = 0; f < 2; ++f) {
        int qidx = qb * 256 + wid * 64 + f * 32 + c;
        const float* qp = Q + ((size_t)b * NPTS + qidx) * 3;
        float x = qp[0], y = qp[1], z = qp[2];
        unsigned short ahx = f2bf(x), ahy = f2bf(y), ahz = f2bf(z);
        if (h == 0) {
            unsigned short alx = f2bf(x - bf2f(ahx));
            unsigned short aly = f2bf(y - bf2f(ahy));
            unsigned short alz = f2bf(z - bf2f(ahz));
            unsigned short one = 0x3F80;
            qfr[f] = short8{(short)ahx,(short)ahy,(short)ahz,
                            (short)alx,(short)aly,(short)alz,(short)one,(short)one};
        } else {
            qfr[f] = short8{(short)ahx,(short)ahy,(short)ahz,0,0,0,0,0};
        }
    }
    __syncthreads();

    f32x16 zero, acc0, acc1;
    #pragma unroll
    for (int r = 0; r < 16; ++r) { zero[r] = 0.0f; acc0[r] = 3.4e38f; acc1[r] = 3.4e38f; }

    for (int i = 0; i < 16; ++i) {            // 32 target tiles, in pairs
        short8 t0 = blds[(2*i  ) * 64 + l];    // lane-contiguous b128
        short8 t1 = blds[(2*i+1) * 64 + l];
        {
            f32x16 d0 = __builtin_amdgcn_mfma_f32_32x32x16_bf16(t0, qfr[0], zero, 0, 0, 0);
            f32x16 d1 = __builtin_amdgcn_mfma_f32_32x32x16_bf16(t1, qfr[0], zero, 0, 0, 0);
            #pragma unroll
            for (int r = 0; r < 16; ++r)
                acc0[r] = fminf(fminf(acc0[r], d0[r]), d1[r]);   // v_min3
        }
        {
            f32x16 d0 = __builtin_amdgcn_mfma_f32_32x32x16_bf16(t0, qfr[1], zero, 0, 0, 0);
            f32x16 d1 = __builtin_amdgcn_mfma_f32_32x32x16_bf16(t1, qfr[1], zero, 0, 0, 0);
            #pragma unroll
            for (int r = 0; r < 16; ++r)
                acc1[r] = fminf(fminf(acc1[r], d0[r]), d1[r]);
        }
    }

    // ---- Lane-local fold (15 min) + 1 cross-half shuffle; store query-min.
    float* pg = pmin + ((size_t)g * NSEG + nseg) * NPTS;
    #pragma unroll
    for (int f = 0; f < 2; ++f) {
        f32x16& a = f ? acc1 : acc0;
        float v = a[0];
        #pragma unroll
        for (int r = 1; r < 16; ++r) v = fminf(v, a[r]);
        v = fminf(v, __shfl_xor(v, 32, 64));   // combine h halves (disjoint rows)
        if (h == 0)
            pg[qb * 256 + wid * 64 + f * 32 + c] = v;   // 128B coalesced
    }
}

// k2: one block per batch (8 x 1024 thr). Per thread: 4 query points;
// min over 4 nsegs (float4, coalesced), + sa computed from raw input,
// clamp, sqrt; both dirs; block-sum -> out[b]. (Validated R11/R12.)
__global__ __launch_bounds__(1024) void reduce_kernel(
    const float* __restrict__ s1, const float* __restrict__ s2,
    const float* __restrict__ pmin, float* __restrict__ out)
{
    int b = blockIdx.x;
    int t = threadIdx.x;               // float4 row-group, 0..1023

    float sum = 0.0f;
    #pragma unroll
    for (int dir = 0; dir < 2; ++dir) {
        int g = dir * NB + b;
        const float4* pg = reinterpret_cast<const float4*>(pmin + (size_t)g * NSEG * NPTS);
        float4 m = pg[t];
        #pragma unroll
        for (int s = 1; s < NSEG; ++s) {
            float4 v = pg[(size_t)s * 1024 + t];
            m.x = fminf(m.x, v.x); m.y = fminf(m.y, v.y);
            m.z = fminf(m.z, v.z); m.w = fminf(m.w, v.w);
        }
        const float* q = (dir ? s2 : s1) + ((size_t)b * NPTS + (size_t)4 * t) * 3;
        const float4* q4 = reinterpret_cast<const float4*>(q);
        float4 f0 = q4[0], f1 = q4[1], f2 = q4[2];
        float sa0 = fmaf(f0.z, f0.z, fmaf(f0.y, f0.y, f0.x * f0.x));
        float sa1 = fmaf(f1.y, f1.y, fmaf(f1.x, f1.x, f0.w * f0.w));
        float sa2 = fmaf(f2.x, f2.x, fmaf(f1.w, f1.w, f1.z * f1.z));
        float sa3 = fmaf(f2.w, f2.w, fmaf(f2.z, f2.z, f2.y * f2.y));
        sum += sqrtf(fmaxf(sa0 + m.x, 0.0f)) + sqrtf(fmaxf(sa1 + m.y, 0.0f))
             + sqrtf(fmaxf(sa2 + m.z, 0.0f)) + sqrtf(fmaxf(sa3 + m.w, 0.0f));
    }

    for (int off = 32; off > 0; off >>= 1)
        sum += __shfl_down(sum, off, 64);

    __shared__ float red[16];
    if ((t & 63) == 0) red[t >> 6] = sum;
    __syncthreads();
    if (t == 0) {
        float tt = 0.0f;
        #pragma unroll
        for (int w = 0; w < 16; ++w) tt += red[w];
        out[b] = tt * (1.0f / (float)NPTS);
    }
}

extern "C" void kernel_launch(void* const* d_in, const int* in_sizes, int n_in,
                              void* d_out, int out_size, void* d_ws, size_t ws_size,
                              hipStream_t stream) {
    const float* set1 = (const float*)d_in[0];
    const float* set2 = (const float*)d_in[1];
    float* out  = (float*)d_out;
    float* pmin = (float*)d_ws;    // 2*NB*NSEG*NPTS*4 = 1 MiB

    mfma_min_kernel<<<16 * 16 * NSEG, 256, 0, stream>>>(set1, set2, pmin);
    reduce_kernel<<<NB, 1024, 0, stream>>>(set1, set2, pmin, out);
}